// Round 5
// baseline (495.411 us; speedup 1.0000x reference)
//
#include <hip/hip_runtime.h>

#define NN 100000
#define NE 1600000

typedef __attribute__((ext_vector_type(8))) short short8;   // 8 bf16 = 4 VGPRs (MFMA A/B frag)
typedef __attribute__((ext_vector_type(4))) float f32x4;    // MFMA C/D frag

// bf16 helpers
static __device__ __forceinline__ unsigned f2bf_rne(float f) {
    unsigned u = __float_as_uint(f);
    return (u + 0x7FFFu + ((u >> 16) & 1u)) >> 16;   // round-to-nearest-even
}
static __device__ __forceinline__ float bf_lo(unsigned u) { return __uint_as_float(u << 16); }
static __device__ __forceinline__ float bf_hi(unsigned u) { return __uint_as_float(u & 0xFFFF0000u); }

// packed[]: one u64 counter per 128B line (stride 16 u64) to kill line-level
// atomic contention. Layout: count in bits 0..23, sum(ew*2^20) in bits 24..63
// (identical numerics to the verified round-1 kernel). packed aliases meta's
// storage (packed dead after k_scan1; meta first written by k_fill, later).
__global__ __launch_bounds__(256) void k_init(unsigned long long* packed, int n) {
    int i = blockIdx.x * 256 + threadIdx.x;
    if (i < n) packed[(size_t)i << 4] = 0ull;
}

// W [128k x 128n] fp32 -> W^T bf16 hi/lo pair, [n][k] row-major so MFMA B-frags
// (lane needs 8 consecutive k at fixed n) are one contiguous 16B load.
__global__ __launch_bounds__(256) void k_prep(const float* __restrict__ W,
                                              ushort* __restrict__ Wth,
                                              ushort* __restrict__ Wtl) {
    int idx = blockIdx.x * 256 + threadIdx.x;   // 0..16383
    int k = idx >> 7, n = idx & 127;
    float w = W[idx];
    unsigned hi = f2bf_rne(w);
    unsigned lo = f2bf_rne(w - bf_lo(hi));      // residual: W ~= hi + lo to ~2^-17 rel
    Wth[n * 128 + k] = (ushort)hi;
    Wtl[n * 128 + k] = (ushort)lo;
}

// ---------------- MFMA GEMM core: 32 rows x 128 cols per block, 4 waves ----------------
// Wave w owns cols [32w, 32w+32): 2x2 frags of 16x16, K-loop 4 steps of 32.
// A staged in LDS bf16 [32][136] (stride 272B = 17*16B: b128-aligned, ~2-way banks).
// B frags loaded straight from global (32KB bf16 W^T stays L1/L2-hot across 3125 blocks).
// SPLIT_A: fp32 A split hi/lo -> Ahi*Whi + Ahi*Wlo + Alo*Whi (~fp32-exact).
template <bool SPLIT_A>
static __device__ __forceinline__ void mfma_tile(const ushort* sAh, const ushort* sAl,
                                                 const ushort* __restrict__ Wth,
                                                 const ushort* __restrict__ Wtl,
                                                 unsigned* __restrict__ Cb,
                                                 size_t r0, int t) {
    int w  = t >> 6;
    int l  = t & 63;
    int lr = l & 15;            // row idx within A-frag / col idx within B-frag
    int lk = (l >> 4) << 3;     // k offset 0,8,16,24 within the 32-wide k-step
    int n0 = w * 32;

    short8 bh[2][4], bl[2][4];
#pragma unroll
    for (int cf = 0; cf < 2; ++cf)
#pragma unroll
        for (int ks = 0; ks < 4; ++ks) {
            int n = n0 + cf * 16 + lr;
            bh[cf][ks] = *(const short8*)&Wth[n * 128 + ks * 32 + lk];
            bl[cf][ks] = *(const short8*)&Wtl[n * 128 + ks * 32 + lk];
        }

    f32x4 zero = {0.f, 0.f, 0.f, 0.f};
    f32x4 acc[2][2] = {{zero, zero}, {zero, zero}};

    __syncthreads();   // sA staging (done by caller) now visible

#pragma unroll
    for (int ks = 0; ks < 4; ++ks) {
        short8 ah[2], al[2];
#pragma unroll
        for (int rf = 0; rf < 2; ++rf) {
            int off = (rf * 16 + lr) * 136 + ks * 32 + lk;
            ah[rf] = *(const short8*)&sAh[off];
            if (SPLIT_A) al[rf] = *(const short8*)&sAl[off];
        }
#pragma unroll
        for (int rf = 0; rf < 2; ++rf)
#pragma unroll
            for (int cf = 0; cf < 2; ++cf) {
                acc[rf][cf] = __builtin_amdgcn_mfma_f32_16x16x32_bf16(ah[rf], bh[cf][ks], acc[rf][cf], 0, 0, 0);
                acc[rf][cf] = __builtin_amdgcn_mfma_f32_16x16x32_bf16(ah[rf], bl[cf][ks], acc[rf][cf], 0, 0, 0);
                if (SPLIT_A)
                    acc[rf][cf] = __builtin_amdgcn_mfma_f32_16x16x32_bf16(al[rf], bh[cf][ks], acc[rf][cf], 0, 0, 0);
            }
    }

    // C/D layout: col = l&15, row = (l>>4)*4 + reg. Pack bf16 col-pairs via shfl_xor(1)
    // (lane^1 holds col^1); even lanes store one u32 word -> same layout k_agg consumes.
#pragma unroll
    for (int rf = 0; rf < 2; ++rf)
#pragma unroll
        for (int cf = 0; cf < 2; ++cf)
#pragma unroll
            for (int r = 0; r < 4; ++r) {
                unsigned b = f2bf_rne(acc[rf][cf][r]);
                unsigned p = (unsigned)__shfl_xor((int)b, 1);
                if (!(l & 1)) {
                    size_t row = r0 + rf * 16 + ((l >> 4) << 2) + r;
                    int c = n0 + cf * 16 + lr;           // even
                    Cb[(row * 128 + c) >> 1] = b | (p << 16);
                }
            }
}

// ---------------- fused: layer-1 MFMA GEMM (fp32 A, split) || edge histogram ----------------
// 9375 blocks = 3125 GEMM (b%3==0) + 6250 pass1. 17 KB LDS -> 8 blocks/CU.
__global__ __launch_bounds__(256) void k_gp(const float* __restrict__ A,
                                            const ushort* __restrict__ Wth,
                                            const ushort* __restrict__ Wtl,
                                            unsigned* __restrict__ Cb,
                                            const int* __restrict__ col,
                                            const float* __restrict__ ew,
                                            unsigned long long* packed,
                                            int* __restrict__ rank, int e) {
    __shared__ alignas(16) ushort sAh[32 * 136];
    __shared__ alignas(16) ushort sAl[32 * 136];
    int b = blockIdx.x;
    int sub = b % 3;
    int q = b / 3;
    int t = threadIdx.x;

    if (sub != 0) {
        int p = q * 2 + sub - 1;            // 0..6249
        int i = p * 256 + t;
        if (i < e) {
            int c = col[i];
            unsigned fe = (unsigned)__float2uint_rn(ew[i] * 1048576.0f);  // 20 frac bits
            unsigned long long inc = ((unsigned long long)fe << 24) | 1ull;
            unsigned long long old = atomicAdd(&packed[(size_t)c << 4], inc);
            rank[i] = (int)(old & 0xFFFFFFull);
        }
        return;
    }

    size_t r0 = (size_t)q * 32;
    const float4* A4 = (const float4*)(A + r0 * 128);
#pragma unroll
    for (int i = 0; i < 4; ++i) {
        int j = t + 256 * i;                // float4 idx 0..1023
        float4 f = A4[j];
        int rr = j >> 5;
        int cc = (j & 31) << 2;
        unsigned h0 = f2bf_rne(f.x), h1 = f2bf_rne(f.y), h2 = f2bf_rne(f.z), h3 = f2bf_rne(f.w);
        unsigned g0 = f2bf_rne(f.x - bf_lo(h0)), g1 = f2bf_rne(f.y - bf_lo(h1));
        unsigned g2 = f2bf_rne(f.z - bf_lo(h2)), g3 = f2bf_rne(f.w - bf_lo(h3));
        *(ushort4*)&sAh[rr * 136 + cc] = make_ushort4((ushort)h0, (ushort)h1, (ushort)h2, (ushort)h3);
        *(ushort4*)&sAl[rr * 136 + cc] = make_ushort4((ushort)g0, (ushort)g1, (ushort)g2, (ushort)g3);
    }
    // mfma_tile's __syncthreads covers sA visibility
    mfma_tile<true>(sAh, sAl, Wth, Wtl, Cb, r0, t);
}

// fused: exclusive scan of counts -> rowptr, plus dinv = rsqrt(deg)
__global__ __launch_bounds__(256) void k_scan1(const unsigned long long* __restrict__ packed,
                                               int* __restrict__ rowptr,
                                               int* __restrict__ part,
                                               float* __restrict__ dinv, int n) {
    __shared__ int s[256];
    int t = threadIdx.x;
    int i = blockIdx.x * 256 + t;
    unsigned long long pk = (i < n) ? packed[(size_t)i << 4] : 0ull;
    int v = (int)(pk & 0xFFFFFFull);
    if (i < n) {
        float deg = 1.0f + (float)(pk >> 24) * (1.0f / 1048576.0f);  // +1 self-loop
        dinv[i] = rsqrtf(deg);
    }
    s[t] = v;
    __syncthreads();
    for (int d = 1; d < 256; d <<= 1) {
        int y = (t >= d) ? s[t - d] : 0;
        __syncthreads();
        s[t] += y;
        __syncthreads();
    }
    if (i < n) rowptr[i] = s[t] - v;
    if (t == 255) part[blockIdx.x] = s[255];
}

__global__ __launch_bounds__(512) void k_scan2(int* part, int m) {
    __shared__ int s[512];
    int t = threadIdx.x;
    int v = (t < m) ? part[t] : 0;
    s[t] = v;
    __syncthreads();
    for (int d = 1; d < 512; d <<= 1) {
        int y = (t >= d) ? s[t - d] : 0;
        __syncthreads();
        s[t] += y;
        __syncthreads();
    }
    if (t < m) part[t] = s[t] - v;
}

__global__ __launch_bounds__(256) void k_scan3(int* rowptr, const int* __restrict__ part, int n, int e) {
    int i = blockIdx.x * 256 + threadIdx.x;
    if (i < n) rowptr[i] += part[blockIdx.x];
    if (i == 0) rowptr[n] = e;
}

// atomic-free CSR fill; (src, wn) packed -> one 8-byte scattered store per edge
__global__ __launch_bounds__(256) void k_fill(const int* __restrict__ row,
                                              const int* __restrict__ col,
                                              const float* __restrict__ ew,
                                              const int* __restrict__ rowptr,
                                              const int* __restrict__ rank,
                                              const float* __restrict__ dinv,
                                              uint2* __restrict__ meta, int e) {
    int i = blockIdx.x * 256 + threadIdx.x;
    if (i < e) {
        int c = col[i];
        int r = row[i];
        int p = rowptr[c] + rank[i];
        float w = dinv[r] * ew[i] * dinv[c];
        meta[p] = make_uint2((unsigned)r, __float_as_uint(w));
    }
}

// ---------------- MFMA GEMM with bf16 A (layers 2,3) -> bf16 out ----------------
__global__ __launch_bounds__(256) void k_gemm_b(const unsigned* __restrict__ Ab,
                                                const ushort* __restrict__ Wth,
                                                const ushort* __restrict__ Wtl,
                                                unsigned* __restrict__ Cb) {
    __shared__ alignas(16) ushort sA[32 * 136];
    int t = threadIdx.x;
    size_t r0 = (size_t)blockIdx.x * 32;

    const uint4* A4 = (const uint4*)(Ab + r0 * 64);   // 8 bf16 per uint4
#pragma unroll
    for (int i = 0; i < 2; ++i) {
        int j = t + 256 * i;          // uint4 idx 0..511
        uint4 u = A4[j];
        int rr = j >> 4;              // 16 uint4 per 128-col row
        int cc = (j & 15) << 3;
        *(uint4*)&sA[rr * 136 + cc] = u;   // 272B stride = 17*16B: aligned
    }
    mfma_tile<false>(sA, nullptr, Wth, Wtl, Cb, r0, t);
}

// ---------------- pull-aggregation over bf16 rows (round-1 verified version) ----------------
// One wave per node; lane owns one bf16 pair. 8 gathers in flight per lane.
__global__ __launch_bounds__(256) void k_agg(const unsigned* __restrict__ XWb,
                                             const int* __restrict__ rowptr,
                                             const uint2* __restrict__ meta,
                                             const float* __restrict__ dinv,
                                             const float* __restrict__ bias,
                                             unsigned* __restrict__ outb,
                                             float* __restrict__ outf, int relu, int n) {
    int lane = threadIdx.x & 63;
    int node = blockIdx.x * 4 + (threadIdx.x >> 6);
    if (node >= n) return;

    float di = dinv[node];
    float selfw = di * di;
    unsigned uself = XWb[(size_t)node * 64 + lane];
    float2 bv = *(const float2*)(bias + lane * 2);
    float ax = fmaf(selfw, bf_lo(uself), bv.x);
    float ay = fmaf(selfw, bf_hi(uself), bv.y);

    int p0 = rowptr[node], p1 = rowptr[node + 1];
    for (int base = p0; base < p1; base += 64) {
        int m = p1 - base; if (m > 64) m = 64;
        int idx = base + (lane < m ? lane : m - 1);
        uint2 mv = meta[idx];
        int sv = (int)mv.x;
        float wv = __uint_as_float(mv.y);
        int j = 0;
        for (; j + 8 <= m; j += 8) {
            int s0 = __shfl(sv, j),     s1 = __shfl(sv, j + 1);
            int s2 = __shfl(sv, j + 2), s3 = __shfl(sv, j + 3);
            int s4 = __shfl(sv, j + 4), s5 = __shfl(sv, j + 5);
            int s6 = __shfl(sv, j + 6), s7 = __shfl(sv, j + 7);
            float w0 = __shfl(wv, j),     w1 = __shfl(wv, j + 1);
            float w2 = __shfl(wv, j + 2), w3 = __shfl(wv, j + 3);
            float w4 = __shfl(wv, j + 4), w5 = __shfl(wv, j + 5);
            float w6 = __shfl(wv, j + 6), w7 = __shfl(wv, j + 7);
            unsigned u0 = XWb[(size_t)s0 * 64 + lane];
            unsigned u1 = XWb[(size_t)s1 * 64 + lane];
            unsigned u2 = XWb[(size_t)s2 * 64 + lane];
            unsigned u3 = XWb[(size_t)s3 * 64 + lane];
            unsigned u4 = XWb[(size_t)s4 * 64 + lane];
            unsigned u5 = XWb[(size_t)s5 * 64 + lane];
            unsigned u6 = XWb[(size_t)s6 * 64 + lane];
            unsigned u7 = XWb[(size_t)s7 * 64 + lane];
            ax = fmaf(w0, bf_lo(u0), ax);  ay = fmaf(w0, bf_hi(u0), ay);
            ax = fmaf(w1, bf_lo(u1), ax);  ay = fmaf(w1, bf_hi(u1), ay);
            ax = fmaf(w2, bf_lo(u2), ax);  ay = fmaf(w2, bf_hi(u2), ay);
            ax = fmaf(w3, bf_lo(u3), ax);  ay = fmaf(w3, bf_hi(u3), ay);
            ax = fmaf(w4, bf_lo(u4), ax);  ay = fmaf(w4, bf_hi(u4), ay);
            ax = fmaf(w5, bf_lo(u5), ax);  ay = fmaf(w5, bf_hi(u5), ay);
            ax = fmaf(w6, bf_lo(u6), ax);  ay = fmaf(w6, bf_hi(u6), ay);
            ax = fmaf(w7, bf_lo(u7), ax);  ay = fmaf(w7, bf_hi(u7), ay);
        }
        for (; j + 4 <= m; j += 4) {
            int s0 = __shfl(sv, j),     s1 = __shfl(sv, j + 1);
            int s2 = __shfl(sv, j + 2), s3 = __shfl(sv, j + 3);
            float w0 = __shfl(wv, j),     w1 = __shfl(wv, j + 1);
            float w2 = __shfl(wv, j + 2), w3 = __shfl(wv, j + 3);
            unsigned u0 = XWb[(size_t)s0 * 64 + lane];
            unsigned u1 = XWb[(size_t)s1 * 64 + lane];
            unsigned u2 = XWb[(size_t)s2 * 64 + lane];
            unsigned u3 = XWb[(size_t)s3 * 64 + lane];
            ax = fmaf(w0, bf_lo(u0), ax);  ay = fmaf(w0, bf_hi(u0), ay);
            ax = fmaf(w1, bf_lo(u1), ax);  ay = fmaf(w1, bf_hi(u1), ay);
            ax = fmaf(w2, bf_lo(u2), ax);  ay = fmaf(w2, bf_hi(u2), ay);
            ax = fmaf(w3, bf_lo(u3), ax);  ay = fmaf(w3, bf_hi(u3), ay);
        }
        for (; j < m; ++j) {
            int s = __shfl(sv, j);
            float w = __shfl(wv, j);
            unsigned u = XWb[(size_t)s * 64 + lane];
            ax = fmaf(w, bf_lo(u), ax);
            ay = fmaf(w, bf_hi(u), ay);
        }
    }
    if (relu) {
        ax = fmaxf(ax, 0.0f);
        ay = fmaxf(ay, 0.0f);
        outb[(size_t)node * 64 + lane] = f2bf_rne(ax) | (f2bf_rne(ay) << 16);
    } else {
        *(float2*)(outf + (size_t)node * 128 + lane * 2) = make_float2(ax, ay);
    }
}

// ---------------- launcher ----------------
extern "C" void kernel_launch(void* const* d_in, const int* in_sizes, int n_in,
                              void* d_out, int out_size, void* d_ws, size_t ws_size,
                              hipStream_t stream) {
    const float* x  = (const float*)d_in[0];
    const int*   ei = (const int*)d_in[1];
    const float* ew = (const float*)d_in[2];
    const float* W1 = (const float*)d_in[3];
    const float* b1 = (const float*)d_in[4];
    const float* W2 = (const float*)d_in[5];
    const float* b2 = (const float*)d_in[6];
    const float* W3 = (const float*)d_in[7];
    const float* b3 = (const float*)d_in[8];
    float* out = (float*)d_out;

    const int n = NN, e = NE;
    const int* row = ei;
    const int* col = ei + e;

    char* ws = (char*)d_ws;
    size_t off = 0;
    auto alloc = [&](size_t bytes) -> void* {
        void* p = ws + off;
        off = (off + bytes + 255) & ~(size_t)255;
        return p;
    };
    unsigned*           hb     = (unsigned*)alloc((size_t)n * 128 * 2);
    unsigned*           xwb    = (unsigned*)alloc((size_t)n * 128 * 2);
    // union: packed (12.8MB, dead after k_scan1) aliases meta (12.8MB, written
    // by k_fill which is stream-ordered after k_scan1). Keeps total ws ~71.6MB.
    void*               uni    =            alloc((size_t)n * 16 * 8);   // == e*8
    unsigned long long* packed = (unsigned long long*)uni;
    uint2*              meta   = (uint2*)uni;
    float*              dinv   = (float*)   alloc((size_t)n * 4);
    int*                rowptr = (int*)     alloc((size_t)(n + 1) * 4);
    int*                rank   = (int*)     alloc((size_t)e * 4);
    int*                part   = (int*)     alloc(512 * 4);
    ushort*             wt     = (ushort*)  alloc(6 * 16384 * 2);  // 3x {W^T hi, W^T lo}
    (void)ws_size; (void)in_sizes; (void)n_in; (void)out_size;

    int nb = (n + 255) / 256;   // 391
    int eb = (e + 255) / 256;   // 6250
    int gb = n / 32;            // 3125
    int ab = (n + 3) / 4;       // 25000

    k_init<<<nb, 256, 0, stream>>>(packed, n);
    k_prep<<<64, 256, 0, stream>>>(W1, wt + 0 * 16384, wt + 1 * 16384);
    k_prep<<<64, 256, 0, stream>>>(W2, wt + 2 * 16384, wt + 3 * 16384);
    k_prep<<<64, 256, 0, stream>>>(W3, wt + 4 * 16384, wt + 5 * 16384);

    k_gp<<<gb + eb, 256, 0, stream>>>(x, wt + 0 * 16384, wt + 1 * 16384, xwb, col, ew, packed, rank, e);
    k_scan1<<<nb, 256, 0, stream>>>(packed, rowptr, part, dinv, n);
    k_scan2<<<1, 512, 0, stream>>>(part, nb);
    k_scan3<<<nb, 256, 0, stream>>>(rowptr, part, n, e);
    k_fill<<<eb, 256, 0, stream>>>(row, col, ew, rowptr, rank, dinv, meta, e);

    // Layer 1 aggregation -> bf16 hb
    k_agg<<<ab, 256, 0, stream>>>(xwb, rowptr, meta, dinv, b1, hb, (float*)nullptr, 1, n);
    // Layer 2
    k_gemm_b<<<gb, 256, 0, stream>>>(hb, wt + 2 * 16384, wt + 3 * 16384, xwb);
    k_agg<<<ab, 256, 0, stream>>>(xwb, rowptr, meta, dinv, b2, hb, (float*)nullptr, 1, n);
    // Layer 3 (fp32 out, no relu)
    k_gemm_b<<<gb, 256, 0, stream>>>(hb, wt + 4 * 16384, wt + 5 * 16384, xwb);
    k_agg<<<ab, 256, 0, stream>>>(xwb, rowptr, meta, dinv, b3, (unsigned*)nullptr, out, 0, n);
}

// Round 6
// 490.408 us; speedup vs baseline: 1.0102x; 1.0102x over previous
//
#include <hip/hip_runtime.h>

#define NN 100000
#define NE 1600000

typedef __attribute__((ext_vector_type(8))) short short8;   // 8 bf16 = 4 VGPRs (MFMA A/B frag)
typedef __attribute__((ext_vector_type(4))) float f32x4;    // MFMA C/D frag

// bf16 helpers
static __device__ __forceinline__ unsigned f2bf_rne(float f) {
    unsigned u = __float_as_uint(f);
    return (u + 0x7FFFu + ((u >> 16) & 1u)) >> 16;   // round-to-nearest-even
}
static __device__ __forceinline__ float bf_lo(unsigned u) { return __uint_as_float(u << 16); }
static __device__ __forceinline__ float bf_hi(unsigned u) { return __uint_as_float(u & 0xFFFF0000u); }

// packed[]: one u64 counter per 128B line (stride 16 u64). Layout: count in
// bits 0..23, sum(ew*2^20) in bits 24..63. packed aliases meta's storage
// (packed dead after k_scan1; meta first written by k_fill, later).
__global__ __launch_bounds__(256) void k_init(unsigned long long* packed, int n) {
    int i = blockIdx.x * 256 + threadIdx.x;
    if (i < n) packed[(size_t)i << 4] = 0ull;
}

// W [128k x 128n] fp32 -> W^T bf16 hi/lo pair, [n][k] row-major so MFMA B-frags
// (lane needs 8 consecutive k at fixed n) are one contiguous 16B load.
__global__ __launch_bounds__(256) void k_prep(const float* __restrict__ W,
                                              ushort* __restrict__ Wth,
                                              ushort* __restrict__ Wtl) {
    int idx = blockIdx.x * 256 + threadIdx.x;   // 0..16383
    int k = idx >> 7, n = idx & 127;
    float w = W[idx];
    unsigned hi = f2bf_rne(w);
    unsigned lo = f2bf_rne(w - bf_lo(hi));      // residual: W ~= hi + lo to ~2^-17 rel
    Wth[n * 128 + k] = (ushort)hi;
    Wtl[n * 128 + k] = (ushort)lo;
}

// ---------------- MFMA GEMM core: 32 rows x 128 cols per block, 4 waves ----------------
// Wave w owns cols [32w, 32w+32): 2x2 frags of 16x16, K-loop 4 steps of 32.
// A staged in LDS bf16 [32][136] (stride 272B = 17*16B: b128-aligned, ~2-way banks).
// B frags loaded straight from global (32KB bf16 W^T stays L1/L2-hot across 3125 blocks).
// SPLIT_A: fp32 A split hi/lo -> Ahi*Whi + Ahi*Wlo + Alo*Whi (~fp32-exact).
template <bool SPLIT_A>
static __device__ __forceinline__ void mfma_tile(const ushort* sAh, const ushort* sAl,
                                                 const ushort* __restrict__ Wth,
                                                 const ushort* __restrict__ Wtl,
                                                 unsigned* __restrict__ Cb,
                                                 size_t r0, int t) {
    int w  = t >> 6;
    int l  = t & 63;
    int lr = l & 15;            // row idx within A-frag / col idx within B-frag
    int lk = (l >> 4) << 3;     // k offset 0,8,16,24 within the 32-wide k-step
    int n0 = w * 32;

    short8 bh[2][4], bl[2][4];
#pragma unroll
    for (int cf = 0; cf < 2; ++cf)
#pragma unroll
        for (int ks = 0; ks < 4; ++ks) {
            int n = n0 + cf * 16 + lr;
            bh[cf][ks] = *(const short8*)&Wth[n * 128 + ks * 32 + lk];
            bl[cf][ks] = *(const short8*)&Wtl[n * 128 + ks * 32 + lk];
        }

    f32x4 zero = {0.f, 0.f, 0.f, 0.f};
    f32x4 acc[2][2] = {{zero, zero}, {zero, zero}};

    __syncthreads();   // sA staging (done by caller) now visible

#pragma unroll
    for (int ks = 0; ks < 4; ++ks) {
        short8 ah[2], al[2];
#pragma unroll
        for (int rf = 0; rf < 2; ++rf) {
            int off = (rf * 16 + lr) * 136 + ks * 32 + lk;
            ah[rf] = *(const short8*)&sAh[off];
            if (SPLIT_A) al[rf] = *(const short8*)&sAl[off];
        }
#pragma unroll
        for (int rf = 0; rf < 2; ++rf)
#pragma unroll
            for (int cf = 0; cf < 2; ++cf) {
                acc[rf][cf] = __builtin_amdgcn_mfma_f32_16x16x32_bf16(ah[rf], bh[cf][ks], acc[rf][cf], 0, 0, 0);
                acc[rf][cf] = __builtin_amdgcn_mfma_f32_16x16x32_bf16(ah[rf], bl[cf][ks], acc[rf][cf], 0, 0, 0);
                if (SPLIT_A)
                    acc[rf][cf] = __builtin_amdgcn_mfma_f32_16x16x32_bf16(al[rf], bh[cf][ks], acc[rf][cf], 0, 0, 0);
            }
    }

    // C/D layout: col = l&15, row = (l>>4)*4 + reg. Pack bf16 col-pairs via shfl_xor(1)
    // (lane^1 holds col^1); even lanes store one u32 word -> same layout k_agg consumes.
#pragma unroll
    for (int rf = 0; rf < 2; ++rf)
#pragma unroll
        for (int cf = 0; cf < 2; ++cf)
#pragma unroll
            for (int r = 0; r < 4; ++r) {
                unsigned b = f2bf_rne(acc[rf][cf][r]);
                unsigned p = (unsigned)__shfl_xor((int)b, 1);
                if (!(l & 1)) {
                    size_t row = r0 + rf * 16 + ((l >> 4) << 2) + r;
                    int c = n0 + cf * 16 + lr;           // even
                    Cb[(row * 128 + c) >> 1] = b | (p << 16);
                }
            }
}

// ---------------- fused: layer-1 MFMA GEMM (fp32 A, split) || edge histogram ----------------
// 9375 blocks = 3125 GEMM (b%3==0) + 6250 pass1. 17 KB LDS -> 8 blocks/CU.
__global__ __launch_bounds__(256) void k_gp(const float* __restrict__ A,
                                            const ushort* __restrict__ Wth,
                                            const ushort* __restrict__ Wtl,
                                            unsigned* __restrict__ Cb,
                                            const int* __restrict__ col,
                                            const float* __restrict__ ew,
                                            unsigned long long* packed,
                                            int* __restrict__ rank, int e) {
    __shared__ alignas(16) ushort sAh[32 * 136];
    __shared__ alignas(16) ushort sAl[32 * 136];
    int b = blockIdx.x;
    int sub = b % 3;
    int q = b / 3;
    int t = threadIdx.x;

    if (sub != 0) {
        int p = q * 2 + sub - 1;            // 0..6249
        int i = p * 256 + t;
        if (i < e) {
            int c = col[i];
            unsigned fe = (unsigned)__float2uint_rn(ew[i] * 1048576.0f);  // 20 frac bits
            unsigned long long inc = ((unsigned long long)fe << 24) | 1ull;
            unsigned long long old = atomicAdd(&packed[(size_t)c << 4], inc);
            rank[i] = (int)(old & 0xFFFFFFull);
        }
        return;
    }

    size_t r0 = (size_t)q * 32;
    const float4* A4 = (const float4*)(A + r0 * 128);
#pragma unroll
    for (int i = 0; i < 4; ++i) {
        int j = t + 256 * i;                // float4 idx 0..1023
        float4 f = A4[j];
        int rr = j >> 5;
        int cc = (j & 31) << 2;
        unsigned h0 = f2bf_rne(f.x), h1 = f2bf_rne(f.y), h2 = f2bf_rne(f.z), h3 = f2bf_rne(f.w);
        unsigned g0 = f2bf_rne(f.x - bf_lo(h0)), g1 = f2bf_rne(f.y - bf_lo(h1));
        unsigned g2 = f2bf_rne(f.z - bf_lo(h2)), g3 = f2bf_rne(f.w - bf_lo(h3));
        *(ushort4*)&sAh[rr * 136 + cc] = make_ushort4((ushort)h0, (ushort)h1, (ushort)h2, (ushort)h3);
        *(ushort4*)&sAl[rr * 136 + cc] = make_ushort4((ushort)g0, (ushort)g1, (ushort)g2, (ushort)g3);
    }
    // mfma_tile's __syncthreads covers sA visibility
    mfma_tile<true>(sAh, sAl, Wth, Wtl, Cb, r0, t);
}

// fused: exclusive scan of counts -> rowptr, plus dinv = rsqrt(deg)
__global__ __launch_bounds__(256) void k_scan1(const unsigned long long* __restrict__ packed,
                                               int* __restrict__ rowptr,
                                               int* __restrict__ part,
                                               float* __restrict__ dinv, int n) {
    __shared__ int s[256];
    int t = threadIdx.x;
    int i = blockIdx.x * 256 + t;
    unsigned long long pk = (i < n) ? packed[(size_t)i << 4] : 0ull;
    int v = (int)(pk & 0xFFFFFFull);
    if (i < n) {
        float deg = 1.0f + (float)(pk >> 24) * (1.0f / 1048576.0f);  // +1 self-loop
        dinv[i] = rsqrtf(deg);
    }
    s[t] = v;
    __syncthreads();
    for (int d = 1; d < 256; d <<= 1) {
        int y = (t >= d) ? s[t - d] : 0;
        __syncthreads();
        s[t] += y;
        __syncthreads();
    }
    if (i < n) rowptr[i] = s[t] - v;
    if (t == 255) part[blockIdx.x] = s[255];
}

__global__ __launch_bounds__(512) void k_scan2(int* part, int m) {
    __shared__ int s[512];
    int t = threadIdx.x;
    int v = (t < m) ? part[t] : 0;
    s[t] = v;
    __syncthreads();
    for (int d = 1; d < 512; d <<= 1) {
        int y = (t >= d) ? s[t - d] : 0;
        __syncthreads();
        s[t] += y;
        __syncthreads();
    }
    if (t < m) part[t] = s[t] - v;
}

__global__ __launch_bounds__(256) void k_scan3(int* rowptr, const int* __restrict__ part, int n, int e) {
    int i = blockIdx.x * 256 + threadIdx.x;
    if (i < n) rowptr[i] += part[blockIdx.x];
    if (i == 0) rowptr[n] = e;
}

// atomic-free CSR fill; (src, wn) packed -> one 8-byte scattered store per edge
__global__ __launch_bounds__(256) void k_fill(const int* __restrict__ row,
                                              const int* __restrict__ col,
                                              const float* __restrict__ ew,
                                              const int* __restrict__ rowptr,
                                              const int* __restrict__ rank,
                                              const float* __restrict__ dinv,
                                              uint2* __restrict__ meta, int e) {
    int i = blockIdx.x * 256 + threadIdx.x;
    if (i < e) {
        int c = col[i];
        int r = row[i];
        int p = rowptr[c] + rank[i];
        float w = dinv[r] * ew[i] * dinv[c];
        meta[p] = make_uint2((unsigned)r, __float_as_uint(w));
    }
}

// ---------------- MFMA GEMM with bf16 A (layers 2,3) -> bf16 out ----------------
__global__ __launch_bounds__(256) void k_gemm_b(const unsigned* __restrict__ Ab,
                                                const ushort* __restrict__ Wth,
                                                const ushort* __restrict__ Wtl,
                                                unsigned* __restrict__ Cb) {
    __shared__ alignas(16) ushort sA[32 * 136];
    int t = threadIdx.x;
    size_t r0 = (size_t)blockIdx.x * 32;

    const uint4* A4 = (const uint4*)(Ab + r0 * 64);   // 8 bf16 per uint4
#pragma unroll
    for (int i = 0; i < 2; ++i) {
        int j = t + 256 * i;          // uint4 idx 0..511
        uint4 u = A4[j];
        int rr = j >> 4;              // 16 uint4 per 128-col row
        int cc = (j & 15) << 3;
        *(uint4*)&sA[rr * 136 + cc] = u;   // 272B stride = 17*16B: aligned
    }
    mfma_tile<false>(sA, nullptr, Wth, Wtl, Cb, r0, t);
}

// ---------------- pull-aggregation over bf16 rows: 2 nodes per wave ----------------
// Half-wave h owns node (2 per wave); lane owns a feature QUAD (uint2 = 8B).
// Each node's edges are accumulated SEQUENTIALLY in CSR order per feature —
// bit-identical association to the verified 1-node/wave version (the round-2
// half-wave variant failed because it split a node's edges across halves and
// reassociated the sum; here a node never leaves its half-wave).
__global__ __launch_bounds__(256) void k_agg(const unsigned* __restrict__ XWb,
                                             const int* __restrict__ rowptr,
                                             const uint2* __restrict__ meta,
                                             const float* __restrict__ dinv,
                                             const float* __restrict__ bias,
                                             unsigned* __restrict__ outb,
                                             float* __restrict__ outf, int relu, int n) {
    int lane = threadIdx.x & 63;
    int h = lane >> 5;          // which node of the pair
    int q = lane & 31;          // feature quad: features 4q..4q+3
    int node = blockIdx.x * 8 + ((threadIdx.x >> 6) << 1) + h;
    if (node >= n) return;      // n = 100000 = 12500*8: never taken, kept for safety

    const uint2* X2 = (const uint2*)XWb;
    float di = dinv[node];
    float selfw = di * di;
    uint2 us = X2[(size_t)node * 32 + q];
    float4 bv = *(const float4*)(bias + q * 4);
    float a0 = fmaf(selfw, bf_lo(us.x), bv.x);
    float a1 = fmaf(selfw, bf_hi(us.x), bv.y);
    float a2 = fmaf(selfw, bf_lo(us.y), bv.z);
    float a3 = fmaf(selfw, bf_hi(us.y), bv.w);

    int p0 = rowptr[node], p1 = rowptr[node + 1];
    int deg = p1 - p0;
    int dmax = max(deg, __shfl_xor(deg, 32));   // wave-uniform (deg uniform per half)

    for (int base = 0; base < dmax; base += 32) {
        int m = deg - base;                      // this half's valid edges in chunk
        if (m > 32) m = 32;
        int mm = dmax - base;                    // wave-max edges in chunk
        if (mm > 32) mm = 32;
        int idx = p0 + base + (q < m ? q : (m > 0 ? m - 1 : 0));
        if (m <= 0) idx = p0;                    // half done: harmless in-range read
        if (idx > NE - 1) idx = NE - 1;          // deg==0 node at array end
        uint2 mv = meta[idx];
        int sv = (int)mv.x;
        float wv = __uint_as_float(mv.y);

        int j = 0;
        for (; j + 4 <= mm; j += 4) {
#pragma unroll
            for (int u = 0; u < 4; ++u) {
                int jj = j + u;
                int s = __shfl(sv, (h << 5) | jj);
                float w = __shfl(wv, (h << 5) | jj);
                w = (jj < m) ? w : 0.0f;         // mask the shorter half's tail
                uint2 u0 = X2[(size_t)s * 32 + q];
                a0 = fmaf(w, bf_lo(u0.x), a0);  a1 = fmaf(w, bf_hi(u0.x), a1);
                a2 = fmaf(w, bf_lo(u0.y), a2);  a3 = fmaf(w, bf_hi(u0.y), a3);
            }
        }
        for (; j < mm; ++j) {
            int s = __shfl(sv, (h << 5) | j);
            float w = __shfl(wv, (h << 5) | j);
            w = (j < m) ? w : 0.0f;
            uint2 u0 = X2[(size_t)s * 32 + q];
            a0 = fmaf(w, bf_lo(u0.x), a0);  a1 = fmaf(w, bf_hi(u0.x), a1);
            a2 = fmaf(w, bf_lo(u0.y), a2);  a3 = fmaf(w, bf_hi(u0.y), a3);
        }
    }

    if (relu) {
        a0 = fmaxf(a0, 0.0f);  a1 = fmaxf(a1, 0.0f);
        a2 = fmaxf(a2, 0.0f);  a3 = fmaxf(a3, 0.0f);
        uint2 o;
        o.x = f2bf_rne(a0) | (f2bf_rne(a1) << 16);
        o.y = f2bf_rne(a2) | (f2bf_rne(a3) << 16);
        ((uint2*)outb)[(size_t)node * 32 + q] = o;
    } else {
        *(float4*)(outf + (size_t)node * 128 + q * 4) = make_float4(a0, a1, a2, a3);
    }
}

// ---------------- launcher ----------------
extern "C" void kernel_launch(void* const* d_in, const int* in_sizes, int n_in,
                              void* d_out, int out_size, void* d_ws, size_t ws_size,
                              hipStream_t stream) {
    const float* x  = (const float*)d_in[0];
    const int*   ei = (const int*)d_in[1];
    const float* ew = (const float*)d_in[2];
    const float* W1 = (const float*)d_in[3];
    const float* b1 = (const float*)d_in[4];
    const float* W2 = (const float*)d_in[5];
    const float* b2 = (const float*)d_in[6];
    const float* W3 = (const float*)d_in[7];
    const float* b3 = (const float*)d_in[8];
    float* out = (float*)d_out;

    const int n = NN, e = NE;
    const int* row = ei;
    const int* col = ei + e;

    char* ws = (char*)d_ws;
    size_t off = 0;
    auto alloc = [&](size_t bytes) -> void* {
        void* p = ws + off;
        off = (off + bytes + 255) & ~(size_t)255;
        return p;
    };
    unsigned*           hb     = (unsigned*)alloc((size_t)n * 128 * 2);
    unsigned*           xwb    = (unsigned*)alloc((size_t)n * 128 * 2);
    // union: packed (12.8MB, dead after k_scan1) aliases meta (12.8MB, written
    // by k_fill which is stream-ordered after k_scan1). Keeps total ws ~71.6MB.
    void*               uni    =            alloc((size_t)n * 16 * 8);   // == e*8
    unsigned long long* packed = (unsigned long long*)uni;
    uint2*              meta   = (uint2*)uni;
    float*              dinv   = (float*)   alloc((size_t)n * 4);
    int*                rowptr = (int*)     alloc((size_t)(n + 1) * 4);
    int*                rank   = (int*)     alloc((size_t)e * 4);
    int*                part   = (int*)     alloc(512 * 4);
    ushort*             wt     = (ushort*)  alloc(6 * 16384 * 2);  // 3x {W^T hi, W^T lo}
    (void)ws_size; (void)in_sizes; (void)n_in; (void)out_size;

    int nb = (n + 255) / 256;   // 391
    int eb = (e + 255) / 256;   // 6250
    int gb = n / 32;            // 3125
    int ab = (n + 7) / 8;       // 12500 (2 nodes per wave, 4 waves per block)

    k_init<<<nb, 256, 0, stream>>>(packed, n);
    k_prep<<<64, 256, 0, stream>>>(W1, wt + 0 * 16384, wt + 1 * 16384);
    k_prep<<<64, 256, 0, stream>>>(W2, wt + 2 * 16384, wt + 3 * 16384);
    k_prep<<<64, 256, 0, stream>>>(W3, wt + 4 * 16384, wt + 5 * 16384);

    k_gp<<<gb + eb, 256, 0, stream>>>(x, wt + 0 * 16384, wt + 1 * 16384, xwb, col, ew, packed, rank, e);
    k_scan1<<<nb, 256, 0, stream>>>(packed, rowptr, part, dinv, n);
    k_scan2<<<1, 512, 0, stream>>>(part, nb);
    k_scan3<<<nb, 256, 0, stream>>>(rowptr, part, n, e);
    k_fill<<<eb, 256, 0, stream>>>(row, col, ew, rowptr, rank, dinv, meta, e);

    // Layer 1 aggregation -> bf16 hb
    k_agg<<<ab, 256, 0, stream>>>(xwb, rowptr, meta, dinv, b1, hb, (float*)nullptr, 1, n);
    // Layer 2
    k_gemm_b<<<gb, 256, 0, stream>>>(hb, wt + 2 * 16384, wt + 3 * 16384, xwb);
    k_agg<<<ab, 256, 0, stream>>>(xwb, rowptr, meta, dinv, b2, hb, (float*)nullptr, 1, n);
    // Layer 3 (fp32 out, no relu)
    k_gemm_b<<<gb, 256, 0, stream>>>(hb, wt + 4 * 16384, wt + 5 * 16384, xwb);
    k_agg<<<ab, 256, 0, stream>>>(xwb, rowptr, meta, dinv, b3, (unsigned*)nullptr, out, 0, n);
}

// Round 7
// 478.260 us; speedup vs baseline: 1.0359x; 1.0254x over previous
//
#include <hip/hip_runtime.h>

#define NN 100000
#define NE 1600000

typedef __attribute__((ext_vector_type(8))) short short8;   // 8 bf16 = 4 VGPRs (MFMA A/B frag)
typedef __attribute__((ext_vector_type(4))) float f32x4;    // MFMA C/D frag

// bf16 helpers
static __device__ __forceinline__ unsigned f2bf_rne(float f) {
    unsigned u = __float_as_uint(f);
    return (u + 0x7FFFu + ((u >> 16) & 1u)) >> 16;   // round-to-nearest-even
}
static __device__ __forceinline__ float bf_lo(unsigned u) { return __uint_as_float(u << 16); }
static __device__ __forceinline__ float bf_hi(unsigned u) { return __uint_as_float(u & 0xFFFF0000u); }

// packed[]: DENSE u64 per node (128B padding measured neutral-to-worse, r5/r6).
// count in bits 0..23, sum(ew*2^20) in bits 24..63. Aliases meta's storage.
// fused: k_init (zero packed) + 3x k_prep (W -> W^T bf16 hi/lo) in one launch.
__global__ __launch_bounds__(256) void k_pre(unsigned long long* packed, int n,
                                             const float* __restrict__ W1,
                                             const float* __restrict__ W2,
                                             const float* __restrict__ W3,
                                             ushort* __restrict__ wt) {
    int b = blockIdx.x;
    int t = threadIdx.x;
    if (b < 391) {
        int i = b * 256 + t;
        if (i < n) packed[i] = 0ull;
        return;
    }
    int pb = b - 391;                    // 0..191
    int wsel = pb >> 6;                  // 0,1,2
    const float* W = (wsel == 0) ? W1 : (wsel == 1) ? W2 : W3;
    ushort* Wth = wt + wsel * 2 * 16384;
    ushort* Wtl = Wth + 16384;
    int idx = (pb & 63) * 256 + t;       // 0..16383
    int k = idx >> 7, nn = idx & 127;
    float w = W[idx];
    unsigned hi = f2bf_rne(w);
    unsigned lo = f2bf_rne(w - bf_lo(hi));   // residual: W ~= hi + lo to ~2^-17 rel
    Wth[nn * 128 + k] = (ushort)hi;
    Wtl[nn * 128 + k] = (ushort)lo;
}

// ---------------- MFMA GEMM core: 32 rows x 128 cols per block, 4 waves ----------------
// Wave w owns cols [32w, 32w+32): 2x2 frags of 16x16, K-loop 4 steps of 32.
// A staged in LDS bf16 [32][136] (stride 272B = 17*16B: b128-aligned, ~2-way banks).
// B frags loaded straight from global (32KB bf16 W^T stays L1/L2-hot).
// SPLIT_A: fp32 A split hi/lo -> Ahi*Whi + Ahi*Wlo + Alo*Whi (~fp32-exact).
template <bool SPLIT_A>
static __device__ __forceinline__ void mfma_tile(const ushort* sAh, const ushort* sAl,
                                                 const ushort* __restrict__ Wth,
                                                 const ushort* __restrict__ Wtl,
                                                 unsigned* __restrict__ Cb,
                                                 size_t r0, int t) {
    int w  = t >> 6;
    int l  = t & 63;
    int lr = l & 15;            // row idx within A-frag / col idx within B-frag
    int lk = (l >> 4) << 3;     // k offset 0,8,16,24 within the 32-wide k-step
    int n0 = w * 32;

    short8 bh[2][4], bl[2][4];
#pragma unroll
    for (int cf = 0; cf < 2; ++cf)
#pragma unroll
        for (int ks = 0; ks < 4; ++ks) {
            int n = n0 + cf * 16 + lr;
            bh[cf][ks] = *(const short8*)&Wth[n * 128 + ks * 32 + lk];
            bl[cf][ks] = *(const short8*)&Wtl[n * 128 + ks * 32 + lk];
        }

    f32x4 zero = {0.f, 0.f, 0.f, 0.f};
    f32x4 acc[2][2] = {{zero, zero}, {zero, zero}};

    __syncthreads();   // sA staging (done by caller) now visible

#pragma unroll
    for (int ks = 0; ks < 4; ++ks) {
        short8 ah[2], al[2];
#pragma unroll
        for (int rf = 0; rf < 2; ++rf) {
            int off = (rf * 16 + lr) * 136 + ks * 32 + lk;
            ah[rf] = *(const short8*)&sAh[off];
            if (SPLIT_A) al[rf] = *(const short8*)&sAl[off];
        }
#pragma unroll
        for (int rf = 0; rf < 2; ++rf)
#pragma unroll
            for (int cf = 0; cf < 2; ++cf) {
                acc[rf][cf] = __builtin_amdgcn_mfma_f32_16x16x32_bf16(ah[rf], bh[cf][ks], acc[rf][cf], 0, 0, 0);
                acc[rf][cf] = __builtin_amdgcn_mfma_f32_16x16x32_bf16(ah[rf], bl[cf][ks], acc[rf][cf], 0, 0, 0);
                if (SPLIT_A)
                    acc[rf][cf] = __builtin_amdgcn_mfma_f32_16x16x32_bf16(al[rf], bh[cf][ks], acc[rf][cf], 0, 0, 0);
            }
    }

    // C/D layout: col = l&15, row = (l>>4)*4 + reg. Pack bf16 col-pairs via shfl_xor(1)
    // (lane^1 holds col^1); even lanes store one u32 word -> same layout k_agg consumes.
#pragma unroll
    for (int rf = 0; rf < 2; ++rf)
#pragma unroll
        for (int cf = 0; cf < 2; ++cf)
#pragma unroll
            for (int r = 0; r < 4; ++r) {
                unsigned b = f2bf_rne(acc[rf][cf][r]);
                unsigned p = (unsigned)__shfl_xor((int)b, 1);
                if (!(l & 1)) {
                    size_t row = r0 + rf * 16 + ((l >> 4) << 2) + r;
                    int c = n0 + cf * 16 + lr;           // even
                    Cb[(row * 128 + c) >> 1] = b | (p << 16);
                }
            }
}

// ---------------- fused: layer-1 MFMA GEMM (fp32 A, split) || edge histogram ----------------
// 9375 blocks = 3125 GEMM (b%3==0) + 6250 pass1. 17 KB LDS -> 8 blocks/CU.
__global__ __launch_bounds__(256) void k_gp(const float* __restrict__ A,
                                            const ushort* __restrict__ Wth,
                                            const ushort* __restrict__ Wtl,
                                            unsigned* __restrict__ Cb,
                                            const int* __restrict__ col,
                                            const float* __restrict__ ew,
                                            unsigned long long* packed,
                                            int* __restrict__ rank, int e) {
    __shared__ alignas(16) ushort sAh[32 * 136];
    __shared__ alignas(16) ushort sAl[32 * 136];
    int b = blockIdx.x;
    int sub = b % 3;
    int q = b / 3;
    int t = threadIdx.x;

    if (sub != 0) {
        int p = q * 2 + sub - 1;            // 0..6249
        int i = p * 256 + t;
        if (i < e) {
            int c = col[i];
            unsigned fe = (unsigned)__float2uint_rn(ew[i] * 1048576.0f);  // 20 frac bits
            unsigned long long inc = ((unsigned long long)fe << 24) | 1ull;
            unsigned long long old = atomicAdd(&packed[c], inc);
            rank[i] = (int)(old & 0xFFFFFFull);
        }
        return;
    }

    size_t r0 = (size_t)q * 32;
    const float4* A4 = (const float4*)(A + r0 * 128);
#pragma unroll
    for (int i = 0; i < 4; ++i) {
        int j = t + 256 * i;                // float4 idx 0..1023
        float4 f = A4[j];
        int rr = j >> 5;
        int cc = (j & 31) << 2;
        unsigned h0 = f2bf_rne(f.x), h1 = f2bf_rne(f.y), h2 = f2bf_rne(f.z), h3 = f2bf_rne(f.w);
        unsigned g0 = f2bf_rne(f.x - bf_lo(h0)), g1 = f2bf_rne(f.y - bf_lo(h1));
        unsigned g2 = f2bf_rne(f.z - bf_lo(h2)), g3 = f2bf_rne(f.w - bf_lo(h3));
        *(ushort4*)&sAh[rr * 136 + cc] = make_ushort4((ushort)h0, (ushort)h1, (ushort)h2, (ushort)h3);
        *(ushort4*)&sAl[rr * 136 + cc] = make_ushort4((ushort)g0, (ushort)g1, (ushort)g2, (ushort)g3);
    }
    // mfma_tile's __syncthreads covers sA visibility
    mfma_tile<true>(sAh, sAl, Wth, Wtl, Cb, r0, t);
}

// fused: exclusive scan of counts -> rowptr, plus dinv = rsqrt(deg)
__global__ __launch_bounds__(256) void k_scan1(const unsigned long long* __restrict__ packed,
                                               int* __restrict__ rowptr,
                                               int* __restrict__ part,
                                               float* __restrict__ dinv, int n) {
    __shared__ int s[256];
    int t = threadIdx.x;
    int i = blockIdx.x * 256 + t;
    unsigned long long pk = (i < n) ? packed[i] : 0ull;
    int v = (int)(pk & 0xFFFFFFull);
    if (i < n) {
        float deg = 1.0f + (float)(pk >> 24) * (1.0f / 1048576.0f);  // +1 self-loop
        dinv[i] = rsqrtf(deg);
    }
    s[t] = v;
    __syncthreads();
    for (int d = 1; d < 256; d <<= 1) {
        int y = (t >= d) ? s[t - d] : 0;
        __syncthreads();
        s[t] += y;
        __syncthreads();
    }
    if (i < n) rowptr[i] = s[t] - v;
    if (t == 255) part[blockIdx.x] = s[255];
}

__global__ __launch_bounds__(512) void k_scan2(int* part, int m) {
    __shared__ int s[512];
    int t = threadIdx.x;
    int v = (t < m) ? part[t] : 0;
    s[t] = v;
    __syncthreads();
    for (int d = 1; d < 512; d <<= 1) {
        int y = (t >= d) ? s[t - d] : 0;
        __syncthreads();
        s[t] += y;
        __syncthreads();
    }
    if (t < m) part[t] = s[t] - v;
}

__global__ __launch_bounds__(256) void k_scan3(int* rowptr, const int* __restrict__ part, int n, int e) {
    int i = blockIdx.x * 256 + threadIdx.x;
    if (i < n) rowptr[i] += part[blockIdx.x];
    if (i == 0) rowptr[n] = e;
}

// atomic-free CSR fill; (src, wn) packed -> one 8-byte scattered store per edge
__global__ __launch_bounds__(256) void k_fill(const int* __restrict__ row,
                                              const int* __restrict__ col,
                                              const float* __restrict__ ew,
                                              const int* __restrict__ rowptr,
                                              const int* __restrict__ rank,
                                              const float* __restrict__ dinv,
                                              uint2* __restrict__ meta, int e) {
    int i = blockIdx.x * 256 + threadIdx.x;
    if (i < e) {
        int c = col[i];
        int r = row[i];
        int p = rowptr[c] + rank[i];
        float w = dinv[r] * ew[i] * dinv[c];
        meta[p] = make_uint2((unsigned)r, __float_as_uint(w));
    }
}

// ---------------- per-node aggregation core (2 nodes/wave, verified r6) ----------------
// Half-wave h owns the node; lane owns feature quad q (uint2 = 8B gathers).
// Accumulation is strictly sequential in CSR order per feature -> bit-identical
// association to the verified 1-node/wave version.
static __device__ __forceinline__ void agg_node(const uint2* __restrict__ X2,
                                                const int* __restrict__ rowptr,
                                                const uint2* __restrict__ meta,
                                                const float* __restrict__ dinv,
                                                const float* __restrict__ bias,
                                                int node, int h, int q,
                                                float& a0, float& a1, float& a2, float& a3) {
    float di = dinv[node];
    float selfw = di * di;
    uint2 us = X2[(size_t)node * 32 + q];
    float4 bv = *(const float4*)(bias + q * 4);
    a0 = fmaf(selfw, bf_lo(us.x), bv.x);
    a1 = fmaf(selfw, bf_hi(us.x), bv.y);
    a2 = fmaf(selfw, bf_lo(us.y), bv.z);
    a3 = fmaf(selfw, bf_hi(us.y), bv.w);

    int p0 = rowptr[node], p1 = rowptr[node + 1];
    int deg = p1 - p0;
    int dmax = max(deg, __shfl_xor(deg, 32));   // wave-uniform (deg uniform per half)

    for (int base = 0; base < dmax; base += 32) {
        int m = deg - base;                      // this half's valid edges in chunk
        if (m > 32) m = 32;
        int mm = dmax - base;                    // wave-max edges in chunk
        if (mm > 32) mm = 32;
        int idx = p0 + base + (q < m ? q : (m > 0 ? m - 1 : 0));
        if (m <= 0) idx = p0;                    // half done: harmless in-range read
        if (idx > NE - 1) idx = NE - 1;          // deg==0 node at array end
        uint2 mv = meta[idx];
        int sv = (int)mv.x;
        float wv = __uint_as_float(mv.y);

        int j = 0;
        for (; j + 4 <= mm; j += 4) {
#pragma unroll
            for (int u = 0; u < 4; ++u) {
                int jj = j + u;
                int s = __shfl(sv, (h << 5) | jj);
                float w = __shfl(wv, (h << 5) | jj);
                w = (jj < m) ? w : 0.0f;         // mask the shorter half's tail
                uint2 u0 = X2[(size_t)s * 32 + q];
                a0 = fmaf(w, bf_lo(u0.x), a0);  a1 = fmaf(w, bf_hi(u0.x), a1);
                a2 = fmaf(w, bf_lo(u0.y), a2);  a3 = fmaf(w, bf_hi(u0.y), a3);
            }
        }
        for (; j < mm; ++j) {
            int s = __shfl(sv, (h << 5) | j);
            float w = __shfl(wv, (h << 5) | j);
            w = (j < m) ? w : 0.0f;
            uint2 u0 = X2[(size_t)s * 32 + q];
            a0 = fmaf(w, bf_lo(u0.x), a0);  a1 = fmaf(w, bf_hi(u0.x), a1);
            a2 = fmaf(w, bf_lo(u0.y), a2);  a3 = fmaf(w, bf_hi(u0.y), a3);
        }
    }
}

// ---------------- fused: aggregation(layer L) + relu/bias + GEMM(layer L+1) ----------------
// Block owns 32 nodes: 4 waves x (4 passes x 2 nodes). Aggregated bf16 rows land
// directly in the LDS A-tile; then the 4-wave MFMA GEMM runs on it. Removes the
// global h round-trip and two kernel launches; MFMA overlaps other blocks' gathers.
__global__ __launch_bounds__(256) void k_aggemm(const unsigned* __restrict__ Xsrc,
                                                const int* __restrict__ rowptr,
                                                const uint2* __restrict__ meta,
                                                const float* __restrict__ dinv,
                                                const float* __restrict__ bias,
                                                const ushort* __restrict__ Wth,
                                                const ushort* __restrict__ Wtl,
                                                unsigned* __restrict__ Cb) {
    __shared__ alignas(16) ushort sA[32 * 136];
    int t = threadIdx.x;
    int lane = t & 63, wid = t >> 6;
    int h = lane >> 5, q = lane & 31;
    const uint2* X2 = (const uint2*)Xsrc;
    size_t r0 = (size_t)blockIdx.x * 32;

#pragma unroll
    for (int p = 0; p < 4; ++p) {
        int ln = (p << 3) + (wid << 1) + h;     // 0..31, full tile covered
        int node = (int)r0 + ln;
        float a0, a1, a2, a3;
        agg_node(X2, rowptr, meta, dinv, bias, node, h, q, a0, a1, a2, a3);
        a0 = fmaxf(a0, 0.0f);  a1 = fmaxf(a1, 0.0f);    // relu (layers 1,2 only)
        a2 = fmaxf(a2, 0.0f);  a3 = fmaxf(a3, 0.0f);
        *(ushort4*)&sA[ln * 136 + (q << 2)] =
            make_ushort4((ushort)f2bf_rne(a0), (ushort)f2bf_rne(a1),
                         (ushort)f2bf_rne(a2), (ushort)f2bf_rne(a3));
    }
    mfma_tile<false>(sA, nullptr, Wth, Wtl, Cb, r0, t);
}

// ---------------- standalone aggregation for layer 3 (fp32 out, no relu) ----------------
__global__ __launch_bounds__(256) void k_agg(const unsigned* __restrict__ XWb,
                                             const int* __restrict__ rowptr,
                                             const uint2* __restrict__ meta,
                                             const float* __restrict__ dinv,
                                             const float* __restrict__ bias,
                                             float* __restrict__ outf, int n) {
    int lane = threadIdx.x & 63;
    int h = lane >> 5;
    int q = lane & 31;
    int node = blockIdx.x * 8 + ((threadIdx.x >> 6) << 1) + h;
    if (node >= n) return;
    float a0, a1, a2, a3;
    agg_node((const uint2*)XWb, rowptr, meta, dinv, bias, node, h, q, a0, a1, a2, a3);
    *(float4*)(outf + (size_t)node * 128 + q * 4) = make_float4(a0, a1, a2, a3);
}

// ---------------- launcher ----------------
extern "C" void kernel_launch(void* const* d_in, const int* in_sizes, int n_in,
                              void* d_out, int out_size, void* d_ws, size_t ws_size,
                              hipStream_t stream) {
    const float* x  = (const float*)d_in[0];
    const int*   ei = (const int*)d_in[1];
    const float* ew = (const float*)d_in[2];
    const float* W1 = (const float*)d_in[3];
    const float* b1 = (const float*)d_in[4];
    const float* W2 = (const float*)d_in[5];
    const float* b2 = (const float*)d_in[6];
    const float* W3 = (const float*)d_in[7];
    const float* b3 = (const float*)d_in[8];
    float* out = (float*)d_out;

    const int n = NN, e = NE;
    const int* row = ei;
    const int* col = ei + e;

    char* ws = (char*)d_ws;
    size_t off = 0;
    auto alloc = [&](size_t bytes) -> void* {
        void* p = ws + off;
        off = (off + bytes + 255) & ~(size_t)255;
        return p;
    };
    unsigned*           hb     = (unsigned*)alloc((size_t)n * 128 * 2);   // xw2 (bf16 pairs)
    unsigned*           xwb    = (unsigned*)alloc((size_t)n * 128 * 2);   // xw1 / xw3
    // union: packed (800KB dense, dead after k_scan1) aliases meta (12.8MB,
    // first written by k_fill which is stream-ordered after k_scan1).
    void*               uni    =            alloc((size_t)e * 8);
    unsigned long long* packed = (unsigned long long*)uni;
    uint2*              meta   = (uint2*)uni;
    float*              dinv   = (float*)   alloc((size_t)n * 4);
    int*                rowptr = (int*)     alloc((size_t)(n + 1) * 4);
    int*                rank   = (int*)     alloc((size_t)e * 4);
    int*                part   = (int*)     alloc(512 * 4);
    ushort*             wt     = (ushort*)  alloc(6 * 16384 * 2);  // 3x {W^T hi, W^T lo}
    (void)ws_size; (void)in_sizes; (void)n_in; (void)out_size;

    int nb = (n + 255) / 256;   // 391
    int eb = (e + 255) / 256;   // 6250
    int gb = n / 32;            // 3125
    int ab = (n + 7) / 8;       // 12500

    // fused zero-init + weight prep: 391 + 192 blocks
    k_pre<<<nb + 192, 256, 0, stream>>>(packed, n, W1, W2, W3, wt);

    k_gp<<<gb + eb, 256, 0, stream>>>(x, wt + 0 * 16384, wt + 1 * 16384, xwb, col, ew, packed, rank, e);
    k_scan1<<<nb, 256, 0, stream>>>(packed, rowptr, part, dinv, n);
    k_scan2<<<1, 512, 0, stream>>>(part, nb);
    k_scan3<<<nb, 256, 0, stream>>>(rowptr, part, n, e);
    k_fill<<<eb, 256, 0, stream>>>(row, col, ew, rowptr, rank, dinv, meta, e);

    // layer-1 agg + relu + layer-2 GEMM  (xw1 -> xw2)
    k_aggemm<<<gb, 256, 0, stream>>>(xwb, rowptr, meta, dinv, b1,
                                     wt + 2 * 16384, wt + 3 * 16384, hb);
    // layer-2 agg + relu + layer-3 GEMM  (xw2 -> xw3)
    k_aggemm<<<gb, 256, 0, stream>>>(hb, rowptr, meta, dinv, b2,
                                     wt + 4 * 16384, wt + 5 * 16384, xwb);
    // layer-3 agg (fp32 out, no relu)
    k_agg<<<ab, 256, 0, stream>>>(xwb, rowptr, meta, dinv, b3, out, n);
}

// Round 8
// 456.323 us; speedup vs baseline: 1.0857x; 1.0481x over previous
//
#include <hip/hip_runtime.h>

#define NN 100000
#define NE 1600000

typedef __attribute__((ext_vector_type(8))) short short8;   // 8 bf16 = 4 VGPRs (MFMA A/B frag)
typedef __attribute__((ext_vector_type(4))) float f32x4;    // MFMA C/D frag

// bf16 helpers
static __device__ __forceinline__ unsigned f2bf_rne(float f) {
    unsigned u = __float_as_uint(f);
    return (u + 0x7FFFu + ((u >> 16) & 1u)) >> 16;   // round-to-nearest-even
}
static __device__ __forceinline__ float bf_lo(unsigned u) { return __uint_as_float(u << 16); }
static __device__ __forceinline__ float bf_hi(unsigned u) { return __uint_as_float(u & 0xFFFF0000u); }

// packed[]: DENSE u64 per node. count in bits 0..23, sum(ew*2^20) in 24..63.
// Aliases meta's storage (packed dead after k_scan1; meta written by k_fill).
// fused: k_init (zero packed) + 3x k_prep (W -> W^T bf16 hi/lo) in one launch.
__global__ __launch_bounds__(256) void k_pre(unsigned long long* packed, int n,
                                             const float* __restrict__ W1,
                                             const float* __restrict__ W2,
                                             const float* __restrict__ W3,
                                             ushort* __restrict__ wt) {
    int b = blockIdx.x;
    int t = threadIdx.x;
    if (b < 391) {
        int i = b * 256 + t;
        if (i < n) packed[i] = 0ull;
        return;
    }
    int pb = b - 391;                    // 0..191
    int wsel = pb >> 6;                  // 0,1,2
    const float* W = (wsel == 0) ? W1 : (wsel == 1) ? W2 : W3;
    ushort* Wth = wt + wsel * 2 * 16384;
    ushort* Wtl = Wth + 16384;
    int idx = (pb & 63) * 256 + t;       // 0..16383
    int k = idx >> 7, nn = idx & 127;
    float w = W[idx];
    unsigned hi = f2bf_rne(w);
    unsigned lo = f2bf_rne(w - bf_lo(hi));   // residual: W ~= hi + lo to ~2^-17 rel
    Wth[nn * 128 + k] = (ushort)hi;
    Wtl[nn * 128 + k] = (ushort)lo;
}

// ---------------- MFMA GEMM core: 32 rows x 128 cols per block, 4 waves ----------------
// Wave w owns cols [32w, 32w+32): 2x2 frags of 16x16, K-loop 4 steps of 32.
// A staged in LDS bf16 [32][136] (stride 272B = 17*16B: b128-aligned, ~2-way banks).
// B frags loaded straight from global (32KB bf16 W^T stays L1/L2-hot).
// SPLIT_A: fp32 A split hi/lo -> Ahi*Whi + Ahi*Wlo + Alo*Whi (~fp32-exact).
template <bool SPLIT_A>
static __device__ __forceinline__ void mfma_tile(const ushort* sAh, const ushort* sAl,
                                                 const ushort* __restrict__ Wth,
                                                 const ushort* __restrict__ Wtl,
                                                 unsigned* __restrict__ Cb,
                                                 size_t r0, int t) {
    int w  = t >> 6;
    int l  = t & 63;
    int lr = l & 15;            // row idx within A-frag / col idx within B-frag
    int lk = (l >> 4) << 3;     // k offset 0,8,16,24 within the 32-wide k-step
    int n0 = w * 32;

    short8 bh[2][4], bl[2][4];
#pragma unroll
    for (int cf = 0; cf < 2; ++cf)
#pragma unroll
        for (int ks = 0; ks < 4; ++ks) {
            int n = n0 + cf * 16 + lr;
            bh[cf][ks] = *(const short8*)&Wth[n * 128 + ks * 32 + lk];
            bl[cf][ks] = *(const short8*)&Wtl[n * 128 + ks * 32 + lk];
        }

    f32x4 zero = {0.f, 0.f, 0.f, 0.f};
    f32x4 acc[2][2] = {{zero, zero}, {zero, zero}};

    __syncthreads();   // sA staging (done by caller) now visible

#pragma unroll
    for (int ks = 0; ks < 4; ++ks) {
        short8 ah[2], al[2];
#pragma unroll
        for (int rf = 0; rf < 2; ++rf) {
            int off = (rf * 16 + lr) * 136 + ks * 32 + lk;
            ah[rf] = *(const short8*)&sAh[off];
            if (SPLIT_A) al[rf] = *(const short8*)&sAl[off];
        }
#pragma unroll
        for (int rf = 0; rf < 2; ++rf)
#pragma unroll
            for (int cf = 0; cf < 2; ++cf) {
                acc[rf][cf] = __builtin_amdgcn_mfma_f32_16x16x32_bf16(ah[rf], bh[cf][ks], acc[rf][cf], 0, 0, 0);
                acc[rf][cf] = __builtin_amdgcn_mfma_f32_16x16x32_bf16(ah[rf], bl[cf][ks], acc[rf][cf], 0, 0, 0);
                if (SPLIT_A)
                    acc[rf][cf] = __builtin_amdgcn_mfma_f32_16x16x32_bf16(al[rf], bh[cf][ks], acc[rf][cf], 0, 0, 0);
            }
    }

    // C/D layout: col = l&15, row = (l>>4)*4 + reg. Pack bf16 col-pairs via shfl_xor(1)
    // (lane^1 holds col^1); even lanes store one u32 word -> same layout k_agg consumes.
#pragma unroll
    for (int rf = 0; rf < 2; ++rf)
#pragma unroll
        for (int cf = 0; cf < 2; ++cf)
#pragma unroll
            for (int r = 0; r < 4; ++r) {
                unsigned b = f2bf_rne(acc[rf][cf][r]);
                unsigned p = (unsigned)__shfl_xor((int)b, 1);
                if (!(l & 1)) {
                    size_t row = r0 + rf * 16 + ((l >> 4) << 2) + r;
                    int c = n0 + cf * 16 + lr;           // even
                    Cb[(row * 128 + c) >> 1] = b | (p << 16);
                }
            }
}

// ---------------- fused: layer-1 MFMA GEMM (fp32 A, split) || edge histogram ----------------
// 9375 blocks = 3125 GEMM (b%3==0) + 6250 pass1. 17 KB LDS -> 8 blocks/CU.
__global__ __launch_bounds__(256) void k_gp(const float* __restrict__ A,
                                            const ushort* __restrict__ Wth,
                                            const ushort* __restrict__ Wtl,
                                            unsigned* __restrict__ Cb,
                                            const int* __restrict__ col,
                                            const float* __restrict__ ew,
                                            unsigned long long* packed,
                                            int* __restrict__ rank, int e) {
    __shared__ alignas(16) ushort sAh[32 * 136];
    __shared__ alignas(16) ushort sAl[32 * 136];
    int b = blockIdx.x;
    int sub = b % 3;
    int q = b / 3;
    int t = threadIdx.x;

    if (sub != 0) {
        int p = q * 2 + sub - 1;            // 0..6249
        int i = p * 256 + t;
        if (i < e) {
            int c = col[i];
            unsigned fe = (unsigned)__float2uint_rn(ew[i] * 1048576.0f);  // 20 frac bits
            unsigned long long inc = ((unsigned long long)fe << 24) | 1ull;
            unsigned long long old = atomicAdd(&packed[c], inc);
            rank[i] = (int)(old & 0xFFFFFFull);
        }
        return;
    }

    size_t r0 = (size_t)q * 32;
    const float4* A4 = (const float4*)(A + r0 * 128);
#pragma unroll
    for (int i = 0; i < 4; ++i) {
        int j = t + 256 * i;                // float4 idx 0..1023
        float4 f = A4[j];
        int rr = j >> 5;
        int cc = (j & 31) << 2;
        unsigned h0 = f2bf_rne(f.x), h1 = f2bf_rne(f.y), h2 = f2bf_rne(f.z), h3 = f2bf_rne(f.w);
        unsigned g0 = f2bf_rne(f.x - bf_lo(h0)), g1 = f2bf_rne(f.y - bf_lo(h1));
        unsigned g2 = f2bf_rne(f.z - bf_lo(h2)), g3 = f2bf_rne(f.w - bf_lo(h3));
        *(ushort4*)&sAh[rr * 136 + cc] = make_ushort4((ushort)h0, (ushort)h1, (ushort)h2, (ushort)h3);
        *(ushort4*)&sAl[rr * 136 + cc] = make_ushort4((ushort)g0, (ushort)g1, (ushort)g2, (ushort)g3);
    }
    // mfma_tile's __syncthreads covers sA visibility
    mfma_tile<true>(sAh, sAl, Wth, Wtl, Cb, r0, t);
}

// fused: exclusive scan of counts -> rowptr, plus dinv = rsqrt(deg)
__global__ __launch_bounds__(256) void k_scan1(const unsigned long long* __restrict__ packed,
                                               int* __restrict__ rowptr,
                                               int* __restrict__ part,
                                               float* __restrict__ dinv, int n) {
    __shared__ int s[256];
    int t = threadIdx.x;
    int i = blockIdx.x * 256 + t;
    unsigned long long pk = (i < n) ? packed[i] : 0ull;
    int v = (int)(pk & 0xFFFFFFull);
    if (i < n) {
        float deg = 1.0f + (float)(pk >> 24) * (1.0f / 1048576.0f);  // +1 self-loop
        dinv[i] = rsqrtf(deg);
    }
    s[t] = v;
    __syncthreads();
    for (int d = 1; d < 256; d <<= 1) {
        int y = (t >= d) ? s[t - d] : 0;
        __syncthreads();
        s[t] += y;
        __syncthreads();
    }
    if (i < n) rowptr[i] = s[t] - v;
    if (t == 255) part[blockIdx.x] = s[255];
}

__global__ __launch_bounds__(512) void k_scan2(int* part, int m) {
    __shared__ int s[512];
    int t = threadIdx.x;
    int v = (t < m) ? part[t] : 0;
    s[t] = v;
    __syncthreads();
    for (int d = 1; d < 512; d <<= 1) {
        int y = (t >= d) ? s[t - d] : 0;
        __syncthreads();
        s[t] += y;
        __syncthreads();
    }
    if (t < m) part[t] = s[t] - v;
}

__global__ __launch_bounds__(256) void k_scan3(int* rowptr, const int* __restrict__ part, int n, int e) {
    int i = blockIdx.x * 256 + threadIdx.x;
    if (i < n) rowptr[i] += part[blockIdx.x];
    if (i == 0) rowptr[n] = e;
}

// atomic-free CSR fill; (src, wn) packed -> one 8-byte scattered store per edge
__global__ __launch_bounds__(256) void k_fill(const int* __restrict__ row,
                                              const int* __restrict__ col,
                                              const float* __restrict__ ew,
                                              const int* __restrict__ rowptr,
                                              const int* __restrict__ rank,
                                              const float* __restrict__ dinv,
                                              uint2* __restrict__ meta, int e) {
    int i = blockIdx.x * 256 + threadIdx.x;
    if (i < e) {
        int c = col[i];
        int r = row[i];
        int p = rowptr[c] + rank[i];
        float w = dinv[r] * ew[i] * dinv[c];
        meta[p] = make_uint2((unsigned)r, __float_as_uint(w));
    }
}

// ---------------- DUAL-node aggregation core (4 nodes/wave, 2 per half-wave) ----------------
// Half-wave h owns nodes {nodeA, nodeB}; lane owns feature quad q (uint2 = 8B).
// Both nodes' chunk loops interleave -> 2x gathers in flight per half-wave.
// Each node's accumulation is strictly sequential in its CSR order per feature:
// bit-identical association to the verified single-node version (r6/r7).
static __device__ __forceinline__ void agg_node2(const uint2* __restrict__ X2,
                                                 const int* __restrict__ rowptr,
                                                 const uint2* __restrict__ meta,
                                                 const float* __restrict__ dinv,
                                                 const float* __restrict__ bias,
                                                 int nodeA, int nodeB, int h, int q,
                                                 float* aA, float* aB) {
    float4 bv = *(const float4*)(bias + q * 4);
    float diA = dinv[nodeA], diB = dinv[nodeB];
    uint2 usA = X2[(size_t)nodeA * 32 + q];
    uint2 usB = X2[(size_t)nodeB * 32 + q];
    float swA = diA * diA, swB = diB * diB;
    aA[0] = fmaf(swA, bf_lo(usA.x), bv.x);  aA[1] = fmaf(swA, bf_hi(usA.x), bv.y);
    aA[2] = fmaf(swA, bf_lo(usA.y), bv.z);  aA[3] = fmaf(swA, bf_hi(usA.y), bv.w);
    aB[0] = fmaf(swB, bf_lo(usB.x), bv.x);  aB[1] = fmaf(swB, bf_hi(usB.x), bv.y);
    aB[2] = fmaf(swB, bf_lo(usB.y), bv.z);  aB[3] = fmaf(swB, bf_hi(usB.y), bv.w);

    int p0A = rowptr[nodeA], degA = rowptr[nodeA + 1] - p0A;
    int p0B = rowptr[nodeB], degB = rowptr[nodeB + 1] - p0B;
    int dloc = max(degA, degB);
    int dm = max(dloc, __shfl_xor(dloc, 32));   // wave-uniform chunk count

    for (int base = 0; base < dm; base += 32) {
        int mA = degA - base;  mA = mA > 32 ? 32 : mA;
        int mB = degB - base;  mB = mB > 32 ? 32 : mB;
        int mm = dm - base;    mm = mm > 32 ? 32 : mm;
        int idxA = p0A + base + (q < mA ? q : (mA > 0 ? mA - 1 : 0));
        if (mA <= 0) idxA = p0A;
        if (idxA > NE - 1) idxA = NE - 1;
        int idxB = p0B + base + (q < mB ? q : (mB > 0 ? mB - 1 : 0));
        if (mB <= 0) idxB = p0B;
        if (idxB > NE - 1) idxB = NE - 1;
        uint2 mvA = meta[idxA];
        uint2 mvB = meta[idxB];
        int svA = (int)mvA.x;  float wvA = __uint_as_float(mvA.y);
        int svB = (int)mvB.x;  float wvB = __uint_as_float(mvB.y);

        int j = 0;
        for (; j + 4 <= mm; j += 4) {
#pragma unroll
            for (int u = 0; u < 4; ++u) {
                int jj = j + u;
                int sA = __shfl(svA, (h << 5) | jj);
                int sB = __shfl(svB, (h << 5) | jj);
                float wA = __shfl(wvA, (h << 5) | jj);
                float wB = __shfl(wvB, (h << 5) | jj);
                wA = (jj < mA) ? wA : 0.0f;
                wB = (jj < mB) ? wB : 0.0f;
                uint2 uA = X2[(size_t)sA * 32 + q];
                uint2 uB = X2[(size_t)sB * 32 + q];
                aA[0] = fmaf(wA, bf_lo(uA.x), aA[0]);  aA[1] = fmaf(wA, bf_hi(uA.x), aA[1]);
                aA[2] = fmaf(wA, bf_lo(uA.y), aA[2]);  aA[3] = fmaf(wA, bf_hi(uA.y), aA[3]);
                aB[0] = fmaf(wB, bf_lo(uB.x), aB[0]);  aB[1] = fmaf(wB, bf_hi(uB.x), aB[1]);
                aB[2] = fmaf(wB, bf_lo(uB.y), aB[2]);  aB[3] = fmaf(wB, bf_hi(uB.y), aB[3]);
            }
        }
        for (; j < mm; ++j) {
            int sA = __shfl(svA, (h << 5) | j);
            int sB = __shfl(svB, (h << 5) | j);
            float wA = __shfl(wvA, (h << 5) | j);
            float wB = __shfl(wvB, (h << 5) | j);
            wA = (j < mA) ? wA : 0.0f;
            wB = (j < mB) ? wB : 0.0f;
            uint2 uA = X2[(size_t)sA * 32 + q];
            uint2 uB = X2[(size_t)sB * 32 + q];
            aA[0] = fmaf(wA, bf_lo(uA.x), aA[0]);  aA[1] = fmaf(wA, bf_hi(uA.x), aA[1]);
            aA[2] = fmaf(wA, bf_lo(uA.y), aA[2]);  aA[3] = fmaf(wA, bf_hi(uA.y), aA[3]);
            aB[0] = fmaf(wB, bf_lo(uB.x), aB[0]);  aB[1] = fmaf(wB, bf_hi(uB.x), aB[1]);
            aB[2] = fmaf(wB, bf_lo(uB.y), aB[2]);  aB[3] = fmaf(wB, bf_hi(uB.y), aB[3]);
        }
    }
}

// ---------------- fused: aggregation(layer L) + relu/bias + GEMM(layer L+1) ----------------
// Block owns 32 nodes: 4 waves x (2 passes x 2 halves x 2 nodes). Aggregated bf16
// rows land directly in the LDS A-tile; then the 4-wave MFMA GEMM runs on it.
__global__ __launch_bounds__(256) void k_aggemm(const unsigned* __restrict__ Xsrc,
                                                const int* __restrict__ rowptr,
                                                const uint2* __restrict__ meta,
                                                const float* __restrict__ dinv,
                                                const float* __restrict__ bias,
                                                const ushort* __restrict__ Wth,
                                                const ushort* __restrict__ Wtl,
                                                unsigned* __restrict__ Cb) {
    __shared__ alignas(16) ushort sA[32 * 136];
    int t = threadIdx.x;
    int lane = t & 63, wid = t >> 6;
    int h = lane >> 5, q = lane & 31;
    const uint2* X2 = (const uint2*)Xsrc;
    size_t r0 = (size_t)blockIdx.x * 32;

#pragma unroll
    for (int p = 0; p < 2; ++p) {
        int ln = (p << 4) + (wid << 2) + (h << 1);   // 0,2,..,30 (+1 = partner)
        int nodeA = (int)r0 + ln;
        int nodeB = nodeA + 1;
        float aA[4], aB[4];
        agg_node2(X2, rowptr, meta, dinv, bias, nodeA, nodeB, h, q, aA, aB);
#pragma unroll
        for (int z = 0; z < 4; ++z) { aA[z] = fmaxf(aA[z], 0.0f); aB[z] = fmaxf(aB[z], 0.0f); }
        *(ushort4*)&sA[ln * 136 + (q << 2)] =
            make_ushort4((ushort)f2bf_rne(aA[0]), (ushort)f2bf_rne(aA[1]),
                         (ushort)f2bf_rne(aA[2]), (ushort)f2bf_rne(aA[3]));
        *(ushort4*)&sA[(ln + 1) * 136 + (q << 2)] =
            make_ushort4((ushort)f2bf_rne(aB[0]), (ushort)f2bf_rne(aB[1]),
                         (ushort)f2bf_rne(aB[2]), (ushort)f2bf_rne(aB[3]));
    }
    mfma_tile<false>(sA, nullptr, Wth, Wtl, Cb, r0, t);
}

// ---------------- standalone aggregation for layer 3 (fp32 out, no relu) ----------------
// Block covers 16 nodes (4 waves x 2 halves x 2 nodes); grid 6250.
__global__ __launch_bounds__(256) void k_agg(const unsigned* __restrict__ XWb,
                                             const int* __restrict__ rowptr,
                                             const uint2* __restrict__ meta,
                                             const float* __restrict__ dinv,
                                             const float* __restrict__ bias,
                                             float* __restrict__ outf, int n) {
    int t = threadIdx.x;
    int lane = t & 63, wid = t >> 6;
    int h = lane >> 5, q = lane & 31;
    int nodeA = blockIdx.x * 16 + (wid << 2) + (h << 1);
    int nodeB = nodeA + 1;
    if (nodeB >= n) return;   // n = 100000 = 6250*16: never taken
    float aA[4], aB[4];
    agg_node2((const uint2*)XWb, rowptr, meta, dinv, bias, nodeA, nodeB, h, q, aA, aB);
    *(float4*)(outf + (size_t)nodeA * 128 + q * 4) = make_float4(aA[0], aA[1], aA[2], aA[3]);
    *(float4*)(outf + (size_t)nodeB * 128 + q * 4) = make_float4(aB[0], aB[1], aB[2], aB[3]);
}

// ---------------- launcher ----------------
extern "C" void kernel_launch(void* const* d_in, const int* in_sizes, int n_in,
                              void* d_out, int out_size, void* d_ws, size_t ws_size,
                              hipStream_t stream) {
    const float* x  = (const float*)d_in[0];
    const int*   ei = (const int*)d_in[1];
    const float* ew = (const float*)d_in[2];
    const float* W1 = (const float*)d_in[3];
    const float* b1 = (const float*)d_in[4];
    const float* W2 = (const float*)d_in[5];
    const float* b2 = (const float*)d_in[6];
    const float* W3 = (const float*)d_in[7];
    const float* b3 = (const float*)d_in[8];
    float* out = (float*)d_out;

    const int n = NN, e = NE;
    const int* row = ei;
    const int* col = ei + e;

    char* ws = (char*)d_ws;
    size_t off = 0;
    auto alloc = [&](size_t bytes) -> void* {
        void* p = ws + off;
        off = (off + bytes + 255) & ~(size_t)255;
        return p;
    };
    unsigned*           hb     = (unsigned*)alloc((size_t)n * 128 * 2);   // xw2 (bf16 pairs)
    unsigned*           xwb    = (unsigned*)alloc((size_t)n * 128 * 2);   // xw1 / xw3
    // union: packed (800KB dense, dead after k_scan1) aliases meta (12.8MB,
    // first written by k_fill which is stream-ordered after k_scan1).
    void*               uni    =            alloc((size_t)e * 8);
    unsigned long long* packed = (unsigned long long*)uni;
    uint2*              meta   = (uint2*)uni;
    float*              dinv   = (float*)   alloc((size_t)n * 4);
    int*                rowptr = (int*)     alloc((size_t)(n + 1) * 4);
    int*                rank   = (int*)     alloc((size_t)e * 4);
    int*                part   = (int*)     alloc(512 * 4);
    ushort*             wt     = (ushort*)  alloc(6 * 16384 * 2);  // 3x {W^T hi, W^T lo}
    (void)ws_size; (void)in_sizes; (void)n_in; (void)out_size;

    int nb = (n + 255) / 256;   // 391
    int eb = (e + 255) / 256;   // 6250
    int gb = n / 32;            // 3125
    int ab = n / 16;            // 6250 (dual-node k_agg)

    // fused zero-init + weight prep: 391 + 192 blocks
    k_pre<<<nb + 192, 256, 0, stream>>>(packed, n, W1, W2, W3, wt);

    k_gp<<<gb + eb, 256, 0, stream>>>(x, wt + 0 * 16384, wt + 1 * 16384, xwb, col, ew, packed, rank, e);
    k_scan1<<<nb, 256, 0, stream>>>(packed, rowptr, part, dinv, n);
    k_scan2<<<1, 512, 0, stream>>>(part, nb);
    k_scan3<<<nb, 256, 0, stream>>>(rowptr, part, n, e);
    k_fill<<<eb, 256, 0, stream>>>(row, col, ew, rowptr, rank, dinv, meta, e);

    // layer-1 agg + relu + layer-2 GEMM  (xw1 -> xw2)
    k_aggemm<<<gb, 256, 0, stream>>>(xwb, rowptr, meta, dinv, b1,
                                     wt + 2 * 16384, wt + 3 * 16384, hb);
    // layer-2 agg + relu + layer-3 GEMM  (xw2 -> xw3)
    k_aggemm<<<gb, 256, 0, stream>>>(hb, rowptr, meta, dinv, b2,
                                     wt + 4 * 16384, wt + 5 * 16384, xwb);
    // layer-3 agg (fp32 out, no relu)
    k_agg<<<ab, 256, 0, stream>>>(xwb, rowptr, meta, dinv, b3, out, n);
}